// Round 15
// baseline (336.996 us; speedup 1.0000x reference)
//
#include <hip/hip_runtime.h>
#include <hip/hip_bf16.h>

#define D 512
#define BM 256
#define BK 32
#define NKT (D/BK)            // 16 K-tiles
#define NT 32                 // 8192 / 256
#define NBLK (NT*(NT+1)/2)    // 528 triangular blocks (528 = 8*66)
#define XCHUNK (NBLK/8)       // 66 blocks per XCD chunk
#define N2ROWS 8192

typedef __attribute__((ext_vector_type(8))) short bf16x8;
typedef __attribute__((ext_vector_type(4))) float f32x4;

__device__ inline unsigned short f2bf(float x) {
    __hip_bfloat16 h = __float2bfloat16(x);
    return __builtin_bit_cast(unsigned short, h);
}

// async global -> LDS, 16B per lane; LDS dest is wave-uniform base + lane*16
__device__ inline void gload16(const unsigned short* g, unsigned short* l) {
    __builtin_amdgcn_global_load_lds(
        (const __attribute__((address_space(1))) unsigned int*)g,
        (__attribute__((address_space(3))) unsigned int*)l,
        16, 0, 0);
}

// Kernel A: row L2-norms, normalized bf16 Yn[2N][D], pos[i]=exp(2*cos); zero total
__global__ __launch_bounds__(128) void prep_kernel(const float* __restrict__ y,
                                                   const float* __restrict__ yh,
                                                   unsigned short* __restrict__ Yn,
                                                   float* __restrict__ pos,
                                                   float* __restrict__ total, int N) {
    const int i = blockIdx.x;
    const int t = threadIdx.x;
    if (i == 0 && t == 1) total[0] = 0.f;
    const float4 a = ((const float4*)(y + (size_t)i * D))[t];
    const float4 b = ((const float4*)(yh + (size_t)i * D))[t];
    float sy = a.x*a.x + a.y*a.y + a.z*a.z + a.w*a.w;
    float sh = b.x*b.x + b.y*b.y + b.z*b.z + b.w*b.w;
    float sd = a.x*b.x + a.y*b.y + a.z*b.z + a.w*b.w;
    #pragma unroll
    for (int o = 32; o > 0; o >>= 1) {
        sy += __shfl_xor(sy, o);
        sh += __shfl_xor(sh, o);
        sd += __shfl_xor(sd, o);
    }
    __shared__ float red[3][2];
    const int wv = t >> 6;
    if ((t & 63) == 0) { red[0][wv] = sy; red[1][wv] = sh; red[2][wv] = sd; }
    __syncthreads();
    sy = red[0][0] + red[0][1];
    sh = red[1][0] + red[1][1];
    sd = red[2][0] + red[2][1];
    const float ny = sqrtf(sy), nh = sqrtf(sh);
    const float ry = 1.f / fmaxf(ny, 1e-12f), rh = 1.f / fmaxf(nh, 1e-12f);
    ushort4 oa, ob;
    oa.x = f2bf(a.x * ry); oa.y = f2bf(a.y * ry); oa.z = f2bf(a.z * ry); oa.w = f2bf(a.w * ry);
    ob.x = f2bf(b.x * rh); ob.y = f2bf(b.y * rh); ob.z = f2bf(b.z * rh); ob.w = f2bf(b.w * rh);
    ((ushort4*)(Yn + (size_t)i * D))[t] = oa;
    ((ushort4*)(Yn + (size_t)(i + N) * D))[t] = ob;
    if (t == 0) {
        const float cs = sd / (fmaxf(ny, 1e-8f) * fmaxf(nh, 1e-8f));
        pos[i] = __expf(2.f * cs);
    }
}

// Kernel B: 256x256 tile, BK=32 -> LDS 70 KB -> 2 blocks/CU (co-resident block
// hides vmcnt/barrier drains; 528 blocks on 512 slots kills grid quantization).
// 2 phases per K-tile (mlo, mhi), 16 MFMA/phase, raw s_barrier + setprio.
// Swizzle (R8-verified at 64B rows): phys chunk = logical ^ ((row>>1)&3);
// source pre-swizzled, same XOR on ds_read -> 0 conflicts.
// Epilogue: LDS cross-wave combine -> single-writer slab stores (no atomics).
__global__ __launch_bounds__(512, 4) void simgemm_kernel(const unsigned short* __restrict__ Yn,
                                                         float* __restrict__ slab) {
    const int t0 = blockIdx.x;
    const int t = (t0 & 7) * XCHUNK + (t0 >> 3);
    int bx = (int)((sqrtf(8.f * (float)t + 1.f) - 1.f) * 0.5f);
    while ((bx + 1) * (bx + 2) / 2 <= t) ++bx;
    while (bx * (bx + 1) / 2 > t) --bx;
    const int by = t - bx * (bx + 1) / 2;

    __shared__ unsigned short As[2][BM * BK];   // 2 x 16 KB
    __shared__ unsigned short Bs[2][BM * BK];   // 2 x 16 KB
    __shared__ float redR[256][4];              // 4 KB
    __shared__ float redC[256][2];              // 2 KB   (70 KB total)
    const int tid = threadIdx.x;
    const int lane = tid & 63;
    const int w = tid >> 6;
    const int wm = (w >> 2) * 128;
    const int wn = (w & 3) * 64;
    const int fr = lane & 15;
    const int fq = lane >> 4;
    const int rowA0 = by * BM, rowB0 = bx * BM;

    f32x4 acc[8][4] = {};

    // staging: row = tid>>2 (0..127 within half), phys chunk = tid&3;
    // source holds logical chunk = (tid&3) ^ ((row>>1)&3) = (tid&3) ^ ((tid>>3)&3)
    const int srow = tid >> 2;
    const int scol = (((tid & 3) ^ ((tid >> 3) & 3)) << 3);
    const int ldsoff = w * 512;   // 512 ushorts = 1024 B per wave per issue

    const unsigned short* gA = Yn + (size_t)(rowA0 + srow) * D + scol;
    const unsigned short* gB = Yn + (size_t)(rowB0 + srow) * D + scol;

    auto STAGE = [&](int buf, int k0) {
        #pragma unroll
        for (int q = 0; q < 2; ++q) {
            gload16(gA + (size_t)q * 128 * D + k0, &As[buf][q * 4096 + ldsoff]);
            gload16(gB + (size_t)q * 128 * D + k0, &Bs[buf][q * 4096 + ldsoff]);
        }
    };
    auto ldA = [&](bf16x8* dst, int cur, int rbase) {
        #pragma unroll
        for (int m = 0; m < 4; ++m) {
            const int row = rbase + m * 16 + fr;
            const int koff = ((fq ^ ((row >> 1) & 3)) << 3);
            dst[m] = *(bf16x8*)&As[cur][row * BK + koff];
        }
    };
    auto ldB = [&](bf16x8* dst, int cur) {
        #pragma unroll
        for (int n = 0; n < 4; ++n) {
            const int row = wn + n * 16 + fr;
            const int koff = ((fq ^ ((row >> 1) & 3)) << 3);
            dst[n] = *(bf16x8*)&Bs[cur][row * BK + koff];
        }
    };

    // prologue: stage K-tile 0
    STAGE(0, 0);
    asm volatile("s_waitcnt vmcnt(0)" ::: "memory");
    __builtin_amdgcn_s_barrier();

    for (int kt = 0; kt < NKT; ++kt) {
        const int cur = kt & 1;
        if (kt < NKT - 1) STAGE(cur ^ 1, (kt + 1) * BK);   // 4 issues for next tile
        bf16x8 af[4], ag[4], bb[4];
        // ---- P1: mlo
        ldA(af, cur, wm);
        ldB(bb, cur);
        __builtin_amdgcn_s_barrier();
        asm volatile("s_waitcnt lgkmcnt(0)" ::: "memory");
        __builtin_amdgcn_s_setprio(1);
        #pragma unroll
        for (int m = 0; m < 4; ++m)
            #pragma unroll
            for (int n = 0; n < 4; ++n)
                acc[m][n] = __builtin_amdgcn_mfma_f32_16x16x32_bf16(af[m], bb[n], acc[m][n], 0, 0, 0);
        __builtin_amdgcn_s_setprio(0);
        __builtin_amdgcn_s_barrier();
        // ---- P2: mhi
        ldA(ag, cur, wm + 64);
        __builtin_amdgcn_s_barrier();
        asm volatile("s_waitcnt lgkmcnt(0)" ::: "memory");
        __builtin_amdgcn_s_setprio(1);
        #pragma unroll
        for (int m = 0; m < 4; ++m)
            #pragma unroll
            for (int n = 0; n < 4; ++n)
                acc[m + 4][n] = __builtin_amdgcn_mfma_f32_16x16x32_bf16(ag[m], bb[n], acc[m + 4][n], 0, 0, 0);
        __builtin_amdgcn_s_setprio(0);
        asm volatile("s_waitcnt vmcnt(0)" ::: "memory");   // next tile landed (no-op on last)
        __builtin_amdgcn_s_barrier();
    }

    const bool diagblk = (bx == by);
    #pragma unroll
    for (int m = 0; m < 8; ++m)
        #pragma unroll
        for (int n = 0; n < 4; ++n)
            #pragma unroll
            for (int r = 0; r < 4; ++r) {
                const float e = __expf(2.f * acc[m][n][r]);
                const bool diag = diagblk && (wm + m * 16 + fq * 4 + r) == (wn + n * 16 + fr);
                acc[m][n][r] = diag ? 0.f : e;
            }
    // per-wave ROW partials (this wave's 64 cols) -> redR[row][wn-quad]
    #pragma unroll
    for (int m = 0; m < 8; ++m)
        #pragma unroll
        for (int r = 0; r < 4; ++r) {
            float v = acc[m][0][r] + acc[m][1][r] + acc[m][2][r] + acc[m][3][r];
            v += __shfl_xor(v, 1);
            v += __shfl_xor(v, 2);
            v += __shfl_xor(v, 4);
            v += __shfl_xor(v, 8);
            if (fr == 0) redR[wm + m * 16 + fq * 4 + r][w & 3] = v;
        }
    // per-wave COL partials (this wave's 128 rows) -> redC[col][wm-half]
    if (!diagblk) {
        #pragma unroll
        for (int n = 0; n < 4; ++n) {
            float v = 0.f;
            #pragma unroll
            for (int m = 0; m < 8; ++m)
                #pragma unroll
                for (int r = 0; r < 4; ++r) v += acc[m][n][r];
            v += __shfl_xor(v, 16);
            v += __shfl_xor(v, 32);
            if (fq == 0) redC[wn + n * 16 + fr][w >> 2] = v;
        }
    }
    __syncthreads();
    // combine across waves; single store per slab slot
    if (tid < 256) {
        const float v = redR[tid][0] + redR[tid][1] + redR[tid][2] + redR[tid][3];
        slab[(size_t)bx * N2ROWS + rowA0 + tid] = v;
    } else if (!diagblk) {
        const int c = tid - 256;
        const float v = redC[c][0] + redC[c][1];
        slab[(size_t)by * N2ROWS + rowB0 + c] = v;
    }
}

// Kernel C1: per-row neg = sum of 32 partials; s = pos/neg; block-reduce; 32 atomics
__global__ __launch_bounds__(256) void reduce_kernel(const float* __restrict__ slab,
                                                     const float* __restrict__ pos,
                                                     float* __restrict__ total, int N) {
    const int i = blockIdx.x * 256 + threadIdx.x;   // 0..8191
    float neg = 0.f;
    #pragma unroll
    for (int q = 0; q < NT; ++q) neg += slab[(size_t)q * N2ROWS + i];
    const float p = pos[i < N ? i : i - N];
    float s = p / neg;
    #pragma unroll
    for (int o = 32; o > 0; o >>= 1) s += __shfl_xor(s, o);
    __shared__ float red[4];
    if ((threadIdx.x & 63) == 0) red[threadIdx.x >> 6] = s;
    __syncthreads();
    if (threadIdx.x == 0) atomicAdd(total, red[0] + red[1] + red[2] + red[3]);
}

// Kernel C2: loss = log(2N) - log(total)
__global__ void final_kernel(const float* __restrict__ total,
                             float* __restrict__ out, int N) {
    out[0] = logf(2.f * (float)N) - logf(total[0]);
}

extern "C" void kernel_launch(void* const* d_in, const int* in_sizes, int n_in,
                              void* d_out, int out_size, void* d_ws, size_t ws_size,
                              hipStream_t stream) {
    const float* y  = (const float*)d_in[0];
    const float* yh = (const float*)d_in[1];
    const int N  = in_sizes[0] / D;   // 4096
    const int N2 = 2 * N;             // 8192

    unsigned short* Yn = (unsigned short*)d_ws;                  // [2N][D] bf16, 8 MB
    const size_t yn_bytes = (size_t)N2 * D * sizeof(unsigned short);
    float* slab  = (float*)((char*)d_ws + yn_bytes);             // [32][8192] = 1 MB
    float* pos   = slab + (size_t)NT * N2ROWS;                   // [N]
    float* total = pos + N;                                      // [1]
    float* out = (float*)d_out;

    prep_kernel<<<N, 128, 0, stream>>>(y, yh, Yn, pos, total, N);
    simgemm_kernel<<<NBLK, 512, 0, stream>>>(Yn, slab);
    reduce_kernel<<<N2 / 256, 256, 0, stream>>>(slab, pos, total, N);
    final_kernel<<<1, 1, 0, stream>>>(total, out, N);
}

// Round 16
// 93.699 us; speedup vs baseline: 3.5966x; 3.5966x over previous
//
#include <hip/hip_runtime.h>
#include <hip/hip_bf16.h>

#define D 512
#define BM 256
#define BK 32
#define NKT (D/BK)            // 16 K-tiles
#define NT 32                 // 8192 / 256
#define NBLK (NT*(NT+1)/2)    // 528 triangular blocks (528 = 8*66)
#define XCHUNK (NBLK/8)       // 66 blocks per XCD chunk
#define N2ROWS 8192

typedef __attribute__((ext_vector_type(8))) short bf16x8;
typedef __attribute__((ext_vector_type(4))) float f32x4;

__device__ inline unsigned short f2bf(float x) {
    __hip_bfloat16 h = __float2bfloat16(x);
    return __builtin_bit_cast(unsigned short, h);
}

// async global -> LDS, 16B per lane; LDS dest is wave-uniform base + lane*16
__device__ inline void gload16(const unsigned short* g, unsigned short* l) {
    __builtin_amdgcn_global_load_lds(
        (const __attribute__((address_space(1))) unsigned int*)g,
        (__attribute__((address_space(3))) unsigned int*)l,
        16, 0, 0);
}

// Kernel A: row L2-norms, normalized bf16 Yn[2N][D], pos[i]=exp(2*cos); zero total
__global__ __launch_bounds__(128) void prep_kernel(const float* __restrict__ y,
                                                   const float* __restrict__ yh,
                                                   unsigned short* __restrict__ Yn,
                                                   float* __restrict__ pos,
                                                   float* __restrict__ total, int N) {
    const int i = blockIdx.x;
    const int t = threadIdx.x;
    if (i == 0 && t == 1) total[0] = 0.f;
    const float4 a = ((const float4*)(y + (size_t)i * D))[t];
    const float4 b = ((const float4*)(yh + (size_t)i * D))[t];
    float sy = a.x*a.x + a.y*a.y + a.z*a.z + a.w*a.w;
    float sh = b.x*b.x + b.y*b.y + b.z*b.z + b.w*b.w;
    float sd = a.x*b.x + a.y*b.y + a.z*b.z + a.w*b.w;
    #pragma unroll
    for (int o = 32; o > 0; o >>= 1) {
        sy += __shfl_xor(sy, o);
        sh += __shfl_xor(sh, o);
        sd += __shfl_xor(sd, o);
    }
    __shared__ float red[3][2];
    const int wv = t >> 6;
    if ((t & 63) == 0) { red[0][wv] = sy; red[1][wv] = sh; red[2][wv] = sd; }
    __syncthreads();
    sy = red[0][0] + red[0][1];
    sh = red[1][0] + red[1][1];
    sd = red[2][0] + red[2][1];
    const float ny = sqrtf(sy), nh = sqrtf(sh);
    const float ry = 1.f / fmaxf(ny, 1e-12f), rh = 1.f / fmaxf(nh, 1e-12f);
    ushort4 oa, ob;
    oa.x = f2bf(a.x * ry); oa.y = f2bf(a.y * ry); oa.z = f2bf(a.z * ry); oa.w = f2bf(a.w * ry);
    ob.x = f2bf(b.x * rh); ob.y = f2bf(b.y * rh); ob.z = f2bf(b.z * rh); ob.w = f2bf(b.w * rh);
    ((ushort4*)(Yn + (size_t)i * D))[t] = oa;
    ((ushort4*)(Yn + (size_t)(i + N) * D))[t] = ob;
    if (t == 0) {
        const float cs = sd / (fmaxf(ny, 1e-8f) * fmaxf(nh, 1e-8f));
        pos[i] = __expf(2.f * cs);
    }
}

// Kernel B: 256x256 tile, BK=32 -> LDS 70 KB -> 2 blocks/CU via LDS/VGPR limits
// (launch_bounds (512,2): VGPR cap 256, kernel ~116, NO SPILL — R15's (512,4)
// capped VGPR at 128 and spilled acc to scratch, 5x regression).
// 2 phases per K-tile, 16 MFMA/phase, raw s_barrier + setprio.
// Swizzle: phys chunk = logical ^ ((row>>1)&3) both sides -> 0 conflicts.
// Epilogue: LDS cross-wave combine -> single-writer slab stores (no atomics).
__global__ __launch_bounds__(512, 2) void simgemm_kernel(const unsigned short* __restrict__ Yn,
                                                         float* __restrict__ slab) {
    const int t0 = blockIdx.x;
    const int t = (t0 & 7) * XCHUNK + (t0 >> 3);
    int bx = (int)((sqrtf(8.f * (float)t + 1.f) - 1.f) * 0.5f);
    while ((bx + 1) * (bx + 2) / 2 <= t) ++bx;
    while (bx * (bx + 1) / 2 > t) --bx;
    const int by = t - bx * (bx + 1) / 2;

    __shared__ unsigned short As[2][BM * BK];   // 2 x 16 KB
    __shared__ unsigned short Bs[2][BM * BK];   // 2 x 16 KB
    __shared__ float redR[256][4];              // 4 KB
    __shared__ float redC[256][2];              // 2 KB   (70 KB total)
    const int tid = threadIdx.x;
    const int lane = tid & 63;
    const int w = tid >> 6;
    const int wm = (w >> 2) * 128;
    const int wn = (w & 3) * 64;
    const int fr = lane & 15;
    const int fq = lane >> 4;
    const int rowA0 = by * BM, rowB0 = bx * BM;

    f32x4 acc[8][4] = {};

    // staging: row = tid>>2 (0..127 within half), phys chunk = tid&3;
    // source holds logical chunk = (tid&3) ^ ((row>>1)&3) = (tid&3) ^ ((tid>>3)&3)
    const int srow = tid >> 2;
    const int scol = (((tid & 3) ^ ((tid >> 3) & 3)) << 3);
    const int ldsoff = w * 512;   // 512 ushorts = 1024 B per wave per issue

    const unsigned short* gA = Yn + (size_t)(rowA0 + srow) * D + scol;
    const unsigned short* gB = Yn + (size_t)(rowB0 + srow) * D + scol;

    auto STAGE = [&](int buf, int k0) {
        #pragma unroll
        for (int q = 0; q < 2; ++q) {
            gload16(gA + (size_t)q * 128 * D + k0, &As[buf][q * 4096 + ldsoff]);
            gload16(gB + (size_t)q * 128 * D + k0, &Bs[buf][q * 4096 + ldsoff]);
        }
    };
    auto ldA = [&](bf16x8* dst, int cur, int rbase) {
        #pragma unroll
        for (int m = 0; m < 4; ++m) {
            const int row = rbase + m * 16 + fr;
            const int koff = ((fq ^ ((row >> 1) & 3)) << 3);
            dst[m] = *(bf16x8*)&As[cur][row * BK + koff];
        }
    };
    auto ldB = [&](bf16x8* dst, int cur) {
        #pragma unroll
        for (int n = 0; n < 4; ++n) {
            const int row = wn + n * 16 + fr;
            const int koff = ((fq ^ ((row >> 1) & 3)) << 3);
            dst[n] = *(bf16x8*)&Bs[cur][row * BK + koff];
        }
    };

    // prologue: stage K-tile 0
    STAGE(0, 0);
    asm volatile("s_waitcnt vmcnt(0)" ::: "memory");
    __builtin_amdgcn_s_barrier();

    for (int kt = 0; kt < NKT; ++kt) {
        const int cur = kt & 1;
        if (kt < NKT - 1) STAGE(cur ^ 1, (kt + 1) * BK);   // 4 issues for next tile
        bf16x8 af[4], ag[4], bb[4];
        // ---- P1: mlo
        ldA(af, cur, wm);
        ldB(bb, cur);
        __builtin_amdgcn_s_barrier();
        asm volatile("s_waitcnt lgkmcnt(0)" ::: "memory");
        __builtin_amdgcn_s_setprio(1);
        #pragma unroll
        for (int m = 0; m < 4; ++m)
            #pragma unroll
            for (int n = 0; n < 4; ++n)
                acc[m][n] = __builtin_amdgcn_mfma_f32_16x16x32_bf16(af[m], bb[n], acc[m][n], 0, 0, 0);
        __builtin_amdgcn_s_setprio(0);
        __builtin_amdgcn_s_barrier();
        // ---- P2: mhi
        ldA(ag, cur, wm + 64);
        __builtin_amdgcn_s_barrier();
        asm volatile("s_waitcnt lgkmcnt(0)" ::: "memory");
        __builtin_amdgcn_s_setprio(1);
        #pragma unroll
        for (int m = 0; m < 4; ++m)
            #pragma unroll
            for (int n = 0; n < 4; ++n)
                acc[m + 4][n] = __builtin_amdgcn_mfma_f32_16x16x32_bf16(ag[m], bb[n], acc[m + 4][n], 0, 0, 0);
        __builtin_amdgcn_s_setprio(0);
        asm volatile("s_waitcnt vmcnt(0)" ::: "memory");   // next tile landed (no-op on last)
        __builtin_amdgcn_s_barrier();
    }

    const bool diagblk = (bx == by);
    #pragma unroll
    for (int m = 0; m < 8; ++m)
        #pragma unroll
        for (int n = 0; n < 4; ++n)
            #pragma unroll
            for (int r = 0; r < 4; ++r) {
                const float e = __expf(2.f * acc[m][n][r]);
                const bool diag = diagblk && (wm + m * 16 + fq * 4 + r) == (wn + n * 16 + fr);
                acc[m][n][r] = diag ? 0.f : e;
            }
    // per-wave ROW partials (this wave's 64 cols) -> redR[row][wn-quad]
    #pragma unroll
    for (int m = 0; m < 8; ++m)
        #pragma unroll
        for (int r = 0; r < 4; ++r) {
            float v = acc[m][0][r] + acc[m][1][r] + acc[m][2][r] + acc[m][3][r];
            v += __shfl_xor(v, 1);
            v += __shfl_xor(v, 2);
            v += __shfl_xor(v, 4);
            v += __shfl_xor(v, 8);
            if (fr == 0) redR[wm + m * 16 + fq * 4 + r][w & 3] = v;
        }
    // per-wave COL partials (this wave's 128 rows) -> redC[col][wm-half]
    if (!diagblk) {
        #pragma unroll
        for (int n = 0; n < 4; ++n) {
            float v = 0.f;
            #pragma unroll
            for (int m = 0; m < 8; ++m)
                #pragma unroll
                for (int r = 0; r < 4; ++r) v += acc[m][n][r];
            v += __shfl_xor(v, 16);
            v += __shfl_xor(v, 32);
            if (fq == 0) redC[wn + n * 16 + fr][w >> 2] = v;
        }
    }
    __syncthreads();
    // combine across waves; single store per slab slot
    if (tid < 256) {
        const float v = redR[tid][0] + redR[tid][1] + redR[tid][2] + redR[tid][3];
        slab[(size_t)bx * N2ROWS + rowA0 + tid] = v;
    } else if (!diagblk) {
        const int c = tid - 256;
        const float v = redC[c][0] + redC[c][1];
        slab[(size_t)by * N2ROWS + rowB0 + c] = v;
    }
}

// Kernel C1: per-row neg = sum of 32 partials; s = pos/neg; block-reduce; 32 atomics
__global__ __launch_bounds__(256) void reduce_kernel(const float* __restrict__ slab,
                                                     const float* __restrict__ pos,
                                                     float* __restrict__ total, int N) {
    const int i = blockIdx.x * 256 + threadIdx.x;   // 0..8191
    float neg = 0.f;
    #pragma unroll
    for (int q = 0; q < NT; ++q) neg += slab[(size_t)q * N2ROWS + i];
    const float p = pos[i < N ? i : i - N];
    float s = p / neg;
    #pragma unroll
    for (int o = 32; o > 0; o >>= 1) s += __shfl_xor(s, o);
    __shared__ float red[4];
    if ((threadIdx.x & 63) == 0) red[threadIdx.x >> 6] = s;
    __syncthreads();
    if (threadIdx.x == 0) atomicAdd(total, red[0] + red[1] + red[2] + red[3]);
}

// Kernel C2: loss = log(2N) - log(total)
__global__ void final_kernel(const float* __restrict__ total,
                             float* __restrict__ out, int N) {
    out[0] = logf(2.f * (float)N) - logf(total[0]);
}

extern "C" void kernel_launch(void* const* d_in, const int* in_sizes, int n_in,
                              void* d_out, int out_size, void* d_ws, size_t ws_size,
                              hipStream_t stream) {
    const float* y  = (const float*)d_in[0];
    const float* yh = (const float*)d_in[1];
    const int N  = in_sizes[0] / D;   // 4096
    const int N2 = 2 * N;             // 8192

    unsigned short* Yn = (unsigned short*)d_ws;                  // [2N][D] bf16, 8 MB
    const size_t yn_bytes = (size_t)N2 * D * sizeof(unsigned short);
    float* slab  = (float*)((char*)d_ws + yn_bytes);             // [32][8192] = 1 MB
    float* pos   = slab + (size_t)NT * N2ROWS;                   // [N]
    float* total = pos + N;                                      // [1]
    float* out = (float*)d_out;

    prep_kernel<<<N, 128, 0, stream>>>(y, yh, Yn, pos, total, N);
    simgemm_kernel<<<NBLK, 512, 0, stream>>>(Yn, slab);
    reduce_kernel<<<N2 / 256, 256, 0, stream>>>(slab, pos, total, N);
    final_kernel<<<1, 1, 0, stream>>>(total, out, N);
}

// Round 17
// 66.760 us; speedup vs baseline: 5.0479x; 1.4035x over previous
//
#include <hip/hip_runtime.h>
#include <hip/hip_bf16.h>

#define D 512
#define BM 256
#define BKB 64                // K-tile bytes per row (64 i8 elements)
#define NKT 8                 // 512 / 64
#define NT 32                 // 8192 / 256
#define NBLK (NT*(NT+1)/2)    // 528 triangular blocks (528 = 8*66)
#define XCHUNK (NBLK/8)       // 66 blocks per XCD chunk
#define N2ROWS 8192

typedef __attribute__((ext_vector_type(4))) int i32x4;

// async global -> LDS, 16B per lane; LDS dest is wave-uniform base + lane*16
__device__ inline void gload16b(const char* g, char* l) {
    __builtin_amdgcn_global_load_lds(
        (const __attribute__((address_space(1))) unsigned int*)g,
        (__attribute__((address_space(3))) unsigned int*)l,
        16, 0, 0);
}

// Kernel A: row L2-norms, per-row-max int8 quantized Qn[2N][D], rscale[2N],
// pos[i]=exp(2*cos) in exact fp32; zeroes total.
// q = rint(127*x/max|row x|)  (independent of the L2 normalization);
// dequant of normalized value: yn = q * rscale,  rscale = maxabs/(127*norm).
__global__ __launch_bounds__(128) void prep_kernel(const float* __restrict__ y,
                                                   const float* __restrict__ yh,
                                                   char* __restrict__ Qn,
                                                   float* __restrict__ rscale,
                                                   float* __restrict__ pos,
                                                   float* __restrict__ total, int N) {
    const int i = blockIdx.x;
    const int t = threadIdx.x;
    if (i == 0 && t == 1) total[0] = 0.f;
    const float4 a = ((const float4*)(y + (size_t)i * D))[t];
    const float4 b = ((const float4*)(yh + (size_t)i * D))[t];
    float sy = a.x*a.x + a.y*a.y + a.z*a.z + a.w*a.w;
    float sh = b.x*b.x + b.y*b.y + b.z*b.z + b.w*b.w;
    float sd = a.x*b.x + a.y*b.y + a.z*b.z + a.w*b.w;
    float ma = fmaxf(fmaxf(fabsf(a.x), fabsf(a.y)), fmaxf(fabsf(a.z), fabsf(a.w)));
    float mb = fmaxf(fmaxf(fabsf(b.x), fabsf(b.y)), fmaxf(fabsf(b.z), fabsf(b.w)));
    #pragma unroll
    for (int o = 32; o > 0; o >>= 1) {
        sy += __shfl_xor(sy, o);
        sh += __shfl_xor(sh, o);
        sd += __shfl_xor(sd, o);
        ma = fmaxf(ma, __shfl_xor(ma, o));
        mb = fmaxf(mb, __shfl_xor(mb, o));
    }
    __shared__ float red[5][2];
    const int wv = t >> 6;
    if ((t & 63) == 0) { red[0][wv] = sy; red[1][wv] = sh; red[2][wv] = sd; red[3][wv] = ma; red[4][wv] = mb; }
    __syncthreads();
    sy = red[0][0] + red[0][1];
    sh = red[1][0] + red[1][1];
    sd = red[2][0] + red[2][1];
    ma = fmaxf(fmaxf(red[3][0], red[3][1]), 1e-20f);
    mb = fmaxf(fmaxf(red[4][0], red[4][1]), 1e-20f);
    const float ny = sqrtf(sy), nh = sqrtf(sh);
    const float ry = 1.f / fmaxf(ny, 1e-12f), rh = 1.f / fmaxf(nh, 1e-12f);
    const float qa = 127.f / ma, qb = 127.f / mb;
    const int ax = (int)rintf(a.x * qa), ay = (int)rintf(a.y * qa),
              az = (int)rintf(a.z * qa), aw = (int)rintf(a.w * qa);
    const int bx_ = (int)rintf(b.x * qb), by_ = (int)rintf(b.y * qb),
              bz = (int)rintf(b.z * qb), bw = (int)rintf(b.w * qb);
    const unsigned int pa = (ax & 0xff) | ((ay & 0xff) << 8) | ((az & 0xff) << 16) | ((aw & 0xff) << 24);
    const unsigned int pb = (bx_ & 0xff) | ((by_ & 0xff) << 8) | ((bz & 0xff) << 16) | ((bw & 0xff) << 24);
    ((unsigned int*)(Qn + (size_t)i * D))[t] = pa;
    ((unsigned int*)(Qn + (size_t)(i + N) * D))[t] = pb;
    if (t == 0) {
        rscale[i]     = ma * ry / 127.f;
        rscale[i + N] = mb * rh / 127.f;
        const float cs = sd / (fmaxf(ny, 1e-8f) * fmaxf(nh, 1e-8f));
        pos[i] = __expf(2.f * cs);
    }
}

// Kernel B: 256x256 tile, int8 K=64-per-inst MFMA, BKB=64 B rows.
// LDS 70 KB -> 2 blocks/CU; 2 phases/K-tile (mlo/mhi), 16 MFMA/phase,
// raw s_barrier + setprio; staging interleaved into phases, vmcnt(0) at
// tile end (co-resident block hides the drain). Swizzle for 64B rows:
// phys 16B-chunk = logical ^ ((row>>2)&3), both sides -> residual 2-way (free).
// Epilogue: dequant via rscale[i]*rscale[j], exp, LDS cross-wave combine,
// single-writer slab stores (no atomics).
__global__ __launch_bounds__(512, 2) void simgemm_kernel(const char* __restrict__ Qn,
                                                         const float* __restrict__ rscale,
                                                         float* __restrict__ slab) {
    const int t0 = blockIdx.x;
    const int t = (t0 & 7) * XCHUNK + (t0 >> 3);
    int bx = (int)((sqrtf(8.f * (float)t + 1.f) - 1.f) * 0.5f);
    while ((bx + 1) * (bx + 2) / 2 <= t) ++bx;
    while (bx * (bx + 1) / 2 > t) --bx;
    const int by = t - bx * (bx + 1) / 2;

    __shared__ char As[2][BM * BKB];   // 2 x 16 KB
    __shared__ char Bs[2][BM * BKB];   // 2 x 16 KB
    __shared__ float redR[256][4];     // 4 KB
    __shared__ float redC[256][2];     // 2 KB   (70 KB total)
    const int tid = threadIdx.x;
    const int lane = tid & 63;
    const int w = tid >> 6;
    const int wm = (w >> 2) * 128;
    const int wn = (w & 3) * 64;
    const int fr = lane & 15;
    const int fq = lane >> 4;
    const int rowA0 = by * BM, rowB0 = bx * BM;

    i32x4 acc[8][4] = {};

    // staging: row = tid>>2 (0..127 per q-half), phys chunk = tid&3;
    // source logical chunk = (tid&3) ^ ((row>>2)&3) = (tid&3) ^ ((tid>>4)&3)
    const int srow = tid >> 2;
    const int scolb = (((tid & 3) ^ ((tid >> 4) & 3)) << 4);
    const int ldsoffb = w * 1024;   // 64 lanes x 16 B per wave-issue

    const char* gA = Qn + (size_t)(rowA0 + srow) * D + scolb;
    const char* gB = Qn + (size_t)(rowB0 + srow) * D + scolb;

    auto SQA = [&](int buf, int k0, int q) {
        gload16b(gA + (size_t)q * 128 * D + k0, &As[buf][q * 8192 + ldsoffb]);
    };
    auto SQB = [&](int buf, int k0, int q) {
        gload16b(gB + (size_t)q * 128 * D + k0, &Bs[buf][q * 8192 + ldsoffb]);
    };
    auto ldA = [&](i32x4* dst, int cur, int rbase) {
        #pragma unroll
        for (int m = 0; m < 4; ++m) {
            const int row = rbase + m * 16 + fr;
            const int off = row * BKB + ((fq ^ ((row >> 2) & 3)) << 4);
            dst[m] = *(i32x4*)&As[cur][off];
        }
    };
    auto ldB = [&](i32x4* dst, int cur) {
        #pragma unroll
        for (int n = 0; n < 4; ++n) {
            const int row = wn + n * 16 + fr;
            const int off = row * BKB + ((fq ^ ((row >> 2) & 3)) << 4);
            dst[n] = *(i32x4*)&Bs[cur][off];
        }
    };

    // prologue: stage K-tile 0 (4 issues)
    #pragma unroll
    for (int q = 0; q < 2; ++q) { SQA(0, 0, q); SQB(0, 0, q); }
    asm volatile("s_waitcnt vmcnt(0)" ::: "memory");
    __builtin_amdgcn_s_barrier();

    for (int kt = 0; kt < NKT; ++kt) {
        const int cur = kt & 1, nxt = cur ^ 1;
        const int k1 = (kt + 1) * BKB;
        i32x4 af[4], ag[4], bb[4];
        // ---- P1: mlo
        ldA(af, cur, wm);
        ldB(bb, cur);
        if (kt < NKT - 1) { SQA(nxt, k1, 0); SQA(nxt, k1, 1); }
        __builtin_amdgcn_s_barrier();
        asm volatile("s_waitcnt lgkmcnt(0)" ::: "memory");
        __builtin_amdgcn_s_setprio(1);
        #pragma unroll
        for (int m = 0; m < 4; ++m)
            #pragma unroll
            for (int n = 0; n < 4; ++n)
                acc[m][n] = __builtin_amdgcn_mfma_i32_16x16x64_i8(af[m], bb[n], acc[m][n], 0, 0, 0);
        __builtin_amdgcn_s_setprio(0);
        __builtin_amdgcn_s_barrier();
        // ---- P2: mhi
        ldA(ag, cur, wm + 64);
        if (kt < NKT - 1) { SQB(nxt, k1, 0); SQB(nxt, k1, 1); }
        __builtin_amdgcn_s_barrier();
        asm volatile("s_waitcnt lgkmcnt(0)" ::: "memory");
        __builtin_amdgcn_s_setprio(1);
        #pragma unroll
        for (int m = 0; m < 4; ++m)
            #pragma unroll
            for (int n = 0; n < 4; ++n)
                acc[m + 4][n] = __builtin_amdgcn_mfma_i32_16x16x64_i8(ag[m], bb[n], acc[m + 4][n], 0, 0, 0);
        __builtin_amdgcn_s_setprio(0);
        asm volatile("s_waitcnt vmcnt(0)" ::: "memory");   // next tile landed
        __builtin_amdgcn_s_barrier();
    }

    const bool diagblk = (bx == by);
    // dequant + exp + fused row/col partial sums
    float rsb4[4];
    #pragma unroll
    for (int n = 0; n < 4; ++n) rsb4[n] = rscale[rowB0 + wn + n * 16 + fr];
    float colv[4] = {0.f, 0.f, 0.f, 0.f};
    #pragma unroll
    for (int m = 0; m < 8; ++m)
        #pragma unroll
        for (int r = 0; r < 4; ++r) {
            const int grow = wm + m * 16 + fq * 4 + r;
            const float rsa = rscale[rowA0 + grow];
            float rv = 0.f;
            #pragma unroll
            for (int n = 0; n < 4; ++n) {
                const float f = (float)acc[m][n][r] * rsa * rsb4[n];
                float e = __expf(2.f * f);
                const bool diag = diagblk && grow == (wn + n * 16 + fr);
                e = diag ? 0.f : e;
                rv += e;
                colv[n] += e;
            }
            rv += __shfl_xor(rv, 1);
            rv += __shfl_xor(rv, 2);
            rv += __shfl_xor(rv, 4);
            rv += __shfl_xor(rv, 8);
            if (fr == 0) redR[grow][w & 3] = rv;
        }
    if (!diagblk) {
        #pragma unroll
        for (int n = 0; n < 4; ++n) {
            float v = colv[n];
            v += __shfl_xor(v, 16);
            v += __shfl_xor(v, 32);
            if (fq == 0) redC[wn + n * 16 + fr][w >> 2] = v;
        }
    }
    __syncthreads();
    // combine across waves; single store per slab slot
    if (tid < 256) {
        const float v = redR[tid][0] + redR[tid][1] + redR[tid][2] + redR[tid][3];
        slab[(size_t)bx * N2ROWS + rowA0 + tid] = v;
    } else if (!diagblk) {
        const int c = tid - 256;
        const float v = redC[c][0] + redC[c][1];
        slab[(size_t)by * N2ROWS + rowB0 + c] = v;
    }
}

// Kernel C1: per-row neg = sum of 32 partials; s = pos/neg; block-reduce; 32 atomics
__global__ __launch_bounds__(256) void reduce_kernel(const float* __restrict__ slab,
                                                     const float* __restrict__ pos,
                                                     float* __restrict__ total, int N) {
    const int i = blockIdx.x * 256 + threadIdx.x;   // 0..8191
    float neg = 0.f;
    #pragma unroll
    for (int q = 0; q < NT; ++q) neg += slab[(size_t)q * N2ROWS + i];
    const float p = pos[i < N ? i : i - N];
    float s = p / neg;
    #pragma unroll
    for (int o = 32; o > 0; o >>= 1) s += __shfl_xor(s, o);
    __shared__ float red[4];
    if ((threadIdx.x & 63) == 0) red[threadIdx.x >> 6] = s;
    __syncthreads();
    if (threadIdx.x == 0) atomicAdd(total, red[0] + red[1] + red[2] + red[3]);
}

// Kernel C2: loss = log(2N) - log(total)
__global__ void final_kernel(const float* __restrict__ total,
                             float* __restrict__ out, int N) {
    out[0] = logf(2.f * (float)N) - logf(total[0]);
}

extern "C" void kernel_launch(void* const* d_in, const int* in_sizes, int n_in,
                              void* d_out, int out_size, void* d_ws, size_t ws_size,
                              hipStream_t stream) {
    const float* y  = (const float*)d_in[0];
    const float* yh = (const float*)d_in[1];
    const int N  = in_sizes[0] / D;   // 4096
    const int N2 = 2 * N;             // 8192

    char* Qn = (char*)d_ws;                                      // [2N][D] i8, 4 MB
    const size_t qn_bytes = (size_t)N2 * D;
    float* slab   = (float*)((char*)d_ws + qn_bytes);            // [32][8192] = 1 MB
    float* pos    = slab + (size_t)NT * N2ROWS;                  // [N]
    float* total  = pos + N;                                     // [1]
    float* rscale = total + 1;                                   // [2N]
    float* out = (float*)d_out;

    prep_kernel<<<N, 128, 0, stream>>>(y, yh, Qn, rscale, pos, total, N);
    simgemm_kernel<<<NBLK, 512, 0, stream>>>(Qn, rscale, slab);
    reduce_kernel<<<N2 / 256, 256, 0, stream>>>(slab, pos, total, N);
    final_kernel<<<1, 1, 0, stream>>>(total, out, N);
}

// Round 18
// 66.007 us; speedup vs baseline: 5.1054x; 1.0114x over previous
//
#include <hip/hip_runtime.h>
#include <hip/hip_bf16.h>

#define D 512
#define BM 256
#define BKB 64                // K-tile bytes per row (64 i8 elements)
#define NKT 8                 // 512 / 64
#define NT 32                 // 8192 / 256
#define NBLK (NT*(NT+1)/2)    // 528 triangular blocks (528 = 8*66)
#define XCHUNK (NBLK/8)       // 66 blocks per XCD chunk
#define N2ROWS 8192

typedef __attribute__((ext_vector_type(4))) int i32x4;

// async global -> LDS, 16B per lane; LDS dest is wave-uniform base + lane*16
__device__ inline void gload16b(const char* g, char* l) {
    __builtin_amdgcn_global_load_lds(
        (const __attribute__((address_space(1))) unsigned int*)g,
        (__attribute__((address_space(3))) unsigned int*)l,
        16, 0, 0);
}

// Kernel A: row L2-norms, per-row-max int8 quantized Qn[2N][D], rscale[2N],
// pos[i]=exp(2*cos) in exact fp32; zeroes total.
__global__ __launch_bounds__(128) void prep_kernel(const float* __restrict__ y,
                                                   const float* __restrict__ yh,
                                                   char* __restrict__ Qn,
                                                   float* __restrict__ rscale,
                                                   float* __restrict__ pos,
                                                   float* __restrict__ total, int N) {
    const int i = blockIdx.x;
    const int t = threadIdx.x;
    if (i == 0 && t == 1) total[0] = 0.f;
    const float4 a = ((const float4*)(y + (size_t)i * D))[t];
    const float4 b = ((const float4*)(yh + (size_t)i * D))[t];
    float sy = a.x*a.x + a.y*a.y + a.z*a.z + a.w*a.w;
    float sh = b.x*b.x + b.y*b.y + b.z*b.z + b.w*b.w;
    float sd = a.x*b.x + a.y*b.y + a.z*b.z + a.w*b.w;
    float ma = fmaxf(fmaxf(fabsf(a.x), fabsf(a.y)), fmaxf(fabsf(a.z), fabsf(a.w)));
    float mb = fmaxf(fmaxf(fabsf(b.x), fabsf(b.y)), fmaxf(fabsf(b.z), fabsf(b.w)));
    #pragma unroll
    for (int o = 32; o > 0; o >>= 1) {
        sy += __shfl_xor(sy, o);
        sh += __shfl_xor(sh, o);
        sd += __shfl_xor(sd, o);
        ma = fmaxf(ma, __shfl_xor(ma, o));
        mb = fmaxf(mb, __shfl_xor(mb, o));
    }
    __shared__ float red[5][2];
    const int wv = t >> 6;
    if ((t & 63) == 0) { red[0][wv] = sy; red[1][wv] = sh; red[2][wv] = sd; red[3][wv] = ma; red[4][wv] = mb; }
    __syncthreads();
    sy = red[0][0] + red[0][1];
    sh = red[1][0] + red[1][1];
    sd = red[2][0] + red[2][1];
    ma = fmaxf(fmaxf(red[3][0], red[3][1]), 1e-20f);
    mb = fmaxf(fmaxf(red[4][0], red[4][1]), 1e-20f);
    const float ny = sqrtf(sy), nh = sqrtf(sh);
    const float ry = 1.f / fmaxf(ny, 1e-12f), rh = 1.f / fmaxf(nh, 1e-12f);
    const float qa = 127.f / ma, qb = 127.f / mb;
    const int ax = (int)rintf(a.x * qa), ay = (int)rintf(a.y * qa),
              az = (int)rintf(a.z * qa), aw = (int)rintf(a.w * qa);
    const int bx_ = (int)rintf(b.x * qb), by_ = (int)rintf(b.y * qb),
              bz = (int)rintf(b.z * qb), bw = (int)rintf(b.w * qb);
    const unsigned int pa = (ax & 0xff) | ((ay & 0xff) << 8) | ((az & 0xff) << 16) | ((aw & 0xff) << 24);
    const unsigned int pb = (bx_ & 0xff) | ((by_ & 0xff) << 8) | ((bz & 0xff) << 16) | ((bw & 0xff) << 24);
    ((unsigned int*)(Qn + (size_t)i * D))[t] = pa;
    ((unsigned int*)(Qn + (size_t)(i + N) * D))[t] = pb;
    if (t == 0) {
        rscale[i]     = ma * ry / 127.f;
        rscale[i + N] = mb * rh / 127.f;
        const float cs = sd / (fmaxf(ny, 1e-8f) * fmaxf(nh, 1e-8f));
        pos[i] = __expf(2.f * cs);
    }
}

// Kernel B: 256x256 tile, int8 K=64 MFMA, BKB=64. MINIMAL-SYNC K-loop:
// intra-tile barriers removed (LDS buffer is stable within a K-tile — no
// inter-wave hazard between mlo/mhi clusters). Per K-tile: stage(kt+1) +
// 12 ds_reads + 32 MFMA, then ONE vmcnt(0) + ONE s_barrier (16 events total
// vs 40 — events measured at ~0.7us each across R14/R16/R17).
// Barrier proof: each wave's reads of buf[cur] complete (lgkm) before its
// MFMAs, which precede the barrier; buf[cur] is only restaged after it.
// Swizzle: phys 16B-chunk = logical ^ ((row>>2)&3) both sides -> ~0 conflicts.
// Epilogue: dequant rscale[i]*rscale[j], exp, LDS cross-wave combine,
// single-writer slab stores (no atomics).
__global__ __launch_bounds__(512, 2) void simgemm_kernel(const char* __restrict__ Qn,
                                                         const float* __restrict__ rscale,
                                                         float* __restrict__ slab) {
    const int t0 = blockIdx.x;
    const int t = (t0 & 7) * XCHUNK + (t0 >> 3);
    int bx = (int)((sqrtf(8.f * (float)t + 1.f) - 1.f) * 0.5f);
    while ((bx + 1) * (bx + 2) / 2 <= t) ++bx;
    while (bx * (bx + 1) / 2 > t) --bx;
    const int by = t - bx * (bx + 1) / 2;

    __shared__ char As[2][BM * BKB];   // 2 x 16 KB
    __shared__ char Bs[2][BM * BKB];   // 2 x 16 KB
    __shared__ float redR[256][4];     // 4 KB
    __shared__ float redC[256][2];     // 2 KB   (70 KB total)
    const int tid = threadIdx.x;
    const int lane = tid & 63;
    const int w = tid >> 6;
    const int wm = (w >> 2) * 128;
    const int wn = (w & 3) * 64;
    const int fr = lane & 15;
    const int fq = lane >> 4;
    const int rowA0 = by * BM, rowB0 = bx * BM;

    i32x4 acc[8][4] = {};

    const int srow = tid >> 2;
    const int scolb = (((tid & 3) ^ ((tid >> 4) & 3)) << 4);
    const int ldsoffb = w * 1024;

    const char* gA = Qn + (size_t)(rowA0 + srow) * D + scolb;
    const char* gB = Qn + (size_t)(rowB0 + srow) * D + scolb;

    auto SQA = [&](int buf, int k0, int q) {
        gload16b(gA + (size_t)q * 128 * D + k0, &As[buf][q * 8192 + ldsoffb]);
    };
    auto SQB = [&](int buf, int k0, int q) {
        gload16b(gB + (size_t)q * 128 * D + k0, &Bs[buf][q * 8192 + ldsoffb]);
    };
    auto ldA = [&](i32x4* dst, int cur, int rbase) {
        #pragma unroll
        for (int m = 0; m < 4; ++m) {
            const int row = rbase + m * 16 + fr;
            const int off = row * BKB + ((fq ^ ((row >> 2) & 3)) << 4);
            dst[m] = *(i32x4*)&As[cur][off];
        }
    };
    auto ldB = [&](i32x4* dst, int cur) {
        #pragma unroll
        for (int n = 0; n < 4; ++n) {
            const int row = wn + n * 16 + fr;
            const int off = row * BKB + ((fq ^ ((row >> 2) & 3)) << 4);
            dst[n] = *(i32x4*)&Bs[cur][off];
        }
    };

    // prologue: stage K-tile 0
    #pragma unroll
    for (int q = 0; q < 2; ++q) { SQA(0, 0, q); SQB(0, 0, q); }
    asm volatile("s_waitcnt vmcnt(0)" ::: "memory");
    __builtin_amdgcn_s_barrier();

    for (int kt = 0; kt < NKT; ++kt) {
        const int cur = kt & 1, nxt = cur ^ 1;
        const int k1 = (kt + 1) * BKB;
        // stage kt+1 (buf[nxt] free: its readers finished before last barrier)
        if (kt < NKT - 1) {
            SQA(nxt, k1, 0); SQA(nxt, k1, 1);
            SQB(nxt, k1, 0); SQB(nxt, k1, 1);
        }
        i32x4 af[4], ag[4], bb[4];
        ldA(af, cur, wm);
        ldB(bb, cur);
        ldA(ag, cur, wm + 64);      // same stable buffer — overlaps cluster 1
        __builtin_amdgcn_s_setprio(1);
        #pragma unroll
        for (int m = 0; m < 4; ++m)
            #pragma unroll
            for (int n = 0; n < 4; ++n)
                acc[m][n] = __builtin_amdgcn_mfma_i32_16x16x64_i8(af[m], bb[n], acc[m][n], 0, 0, 0);
        #pragma unroll
        for (int m = 0; m < 4; ++m)
            #pragma unroll
            for (int n = 0; n < 4; ++n)
                acc[m + 4][n] = __builtin_amdgcn_mfma_i32_16x16x64_i8(ag[m], bb[n], acc[m + 4][n], 0, 0, 0);
        __builtin_amdgcn_s_setprio(0);
        asm volatile("s_waitcnt vmcnt(0)" ::: "memory");   // kt+1 staged
        __builtin_amdgcn_s_barrier();                      // all reads of cur done
    }

    const bool diagblk = (bx == by);
    // dequant + exp + fused row/col partial sums
    float rsb4[4];
    #pragma unroll
    for (int n = 0; n < 4; ++n) rsb4[n] = rscale[rowB0 + wn + n * 16 + fr];
    float colv[4] = {0.f, 0.f, 0.f, 0.f};
    #pragma unroll
    for (int m = 0; m < 8; ++m)
        #pragma unroll
        for (int r = 0; r < 4; ++r) {
            const int grow = wm + m * 16 + fq * 4 + r;
            const float rsa = rscale[rowA0 + grow];
            float rv = 0.f;
            #pragma unroll
            for (int n = 0; n < 4; ++n) {
                const float f = (float)acc[m][n][r] * rsa * rsb4[n];
                float e = __expf(2.f * f);
                const bool diag = diagblk && grow == (wn + n * 16 + fr);
                e = diag ? 0.f : e;
                rv += e;
                colv[n] += e;
            }
            rv += __shfl_xor(rv, 1);
            rv += __shfl_xor(rv, 2);
            rv += __shfl_xor(rv, 4);
            rv += __shfl_xor(rv, 8);
            if (fr == 0) redR[grow][w & 3] = rv;
        }
    if (!diagblk) {
        #pragma unroll
        for (int n = 0; n < 4; ++n) {
            float v = colv[n];
            v += __shfl_xor(v, 16);
            v += __shfl_xor(v, 32);
            if (fq == 0) redC[wn + n * 16 + fr][w >> 2] = v;
        }
    }
    __syncthreads();
    if (tid < 256) {
        const float v = redR[tid][0] + redR[tid][1] + redR[tid][2] + redR[tid][3];
        slab[(size_t)bx * N2ROWS + rowA0 + tid] = v;
    } else if (!diagblk) {
        const int c = tid - 256;
        const float v = redC[c][0] + redC[c][1];
        slab[(size_t)by * N2ROWS + rowB0 + c] = v;
    }
}

// Kernel C1: per-row neg = sum of 32 partials; s = pos/neg; block-reduce; 32 atomics
__global__ __launch_bounds__(256) void reduce_kernel(const float* __restrict__ slab,
                                                     const float* __restrict__ pos,
                                                     float* __restrict__ total, int N) {
    const int i = blockIdx.x * 256 + threadIdx.x;   // 0..8191
    float neg = 0.f;
    #pragma unroll
    for (int q = 0; q < NT; ++q) neg += slab[(size_t)q * N2ROWS + i];
    const float p = pos[i < N ? i : i - N];
    float s = p / neg;
    #pragma unroll
    for (int o = 32; o > 0; o >>= 1) s += __shfl_xor(s, o);
    __shared__ float red[4];
    if ((threadIdx.x & 63) == 0) red[threadIdx.x >> 6] = s;
    __syncthreads();
    if (threadIdx.x == 0) atomicAdd(total, red[0] + red[1] + red[2] + red[3]);
}

// Kernel C2: loss = log(2N) - log(total)
__global__ void final_kernel(const float* __restrict__ total,
                             float* __restrict__ out, int N) {
    out[0] = logf(2.f * (float)N) - logf(total[0]);
}

extern "C" void kernel_launch(void* const* d_in, const int* in_sizes, int n_in,
                              void* d_out, int out_size, void* d_ws, size_t ws_size,
                              hipStream_t stream) {
    const float* y  = (const float*)d_in[0];
    const float* yh = (const float*)d_in[1];
    const int N  = in_sizes[0] / D;   // 4096
    const int N2 = 2 * N;             // 8192

    char* Qn = (char*)d_ws;                                      // [2N][D] i8, 4 MB
    const size_t qn_bytes = (size_t)N2 * D;
    float* slab   = (float*)((char*)d_ws + qn_bytes);            // [32][8192] = 1 MB
    float* pos    = slab + (size_t)NT * N2ROWS;                  // [N]
    float* total  = pos + N;                                     // [1]
    float* rscale = total + 1;                                   // [2N]
    float* out = (float*)d_out;

    prep_kernel<<<N, 128, 0, stream>>>(y, yh, Qn, rscale, pos, total, N);
    simgemm_kernel<<<NBLK, 512, 0, stream>>>(Qn, rscale, slab);
    reduce_kernel<<<N2 / 256, 256, 0, stream>>>(slab, pos, total, N);
    final_kernel<<<1, 1, 0, stream>>>(total, out, N);
}